// Round 3
// baseline (56.918 us; speedup 1.0000x reference)
//
#include <hip/hip_runtime.h>
#include <math.h>

#define IMG_H  384
#define IMG_W  384
#define IMG_HW (IMG_H * IMG_W)
#define NB     4
#define NC     3
#define NK     48
#define NH     24          /* taps per lane-half */

typedef float f2 __attribute__((ext_vector_type(2)));

struct PosAdd { float v[NK]; };

/* 8B-aligned pair load: caller guarantees even offset from a 16B-aligned base */
__device__ __forceinline__ f2 ld2(const float* __restrict__ p) {
    return *(const f2* __restrict__)p;
}

/* left pair at column a (even in interior); clamp-at-0 scalar fallback at edge */
__device__ __forceinline__ f2 ldP(const float* __restrict__ rowp, int a) {
    if (a >= 0) return ld2(rowp + a);
    f2 r;
    r.x = rowp[0];
    r.y = rowp[a + 1 > 0 ? a + 1 : 0];
    return r;
}

/* right pair at column b (even in interior); clamp-at-W-1 scalar fallback at edge */
__device__ __forceinline__ f2 ldQ(const float* __restrict__ rowp, int bq) {
    if (bq + 1 <= IMG_W - 1) return ld2(rowp + bq);
    f2 r;
    r.x = rowp[bq <= IMG_W - 1 ? bq : IMG_W - 1];
    r.y = rowp[IMG_W - 1];
    return r;
}

__global__ __launch_bounds__(256) void LLA_41412074668179_kernel(
    const float* __restrict__ imgs, float* __restrict__ out, PosAdd pa)
{
    const int tid  = threadIdx.x;
    const int lane = tid & 63;
    const int t    = lane >> 5;              // 0 -> dil{1,2,4}=k0..23, 1 -> dil{8,12,24}=k24..47

    // XCD-chunked swizzle: 2304 blocks = 8 XCDs x 288 (contiguous 192-row chunks per XCD)
    const int lb = (blockIdx.x & 7) * 288 + (blockIdx.x >> 3);

    // 2 consecutive pixels per thread, w0 even; half-wave covers 64 consecutive px,
    // both halves same pixels. 64-px segments never straddle a row (384 % 64 == 0).
    const int px0 = lb * 256 + (tid >> 6) * 64 + (lane & 31) * 2;
    const int w0 = px0 % IMG_W;
    const int hb = px0 / IMG_W;
    const int h  = hb % IMG_H;
    const int b  = hb / IMG_H;

    const int dils[3] = { t ? 8 : 1, t ? 12 : 2, t ? 24 : 4 };
    const int od = t ? 0 : 1;                // di==0 dilation is odd only for t==0 (d=1)

    const int r0 = h * IMG_W;
    int rm[3], rp[3];
#pragma unroll
    for (int di = 0; di < 3; ++di) {
        const int d = dils[di];
        rm[di] = max(h - d, 0) * IMG_W;
        rp[di] = min(h + d, IMG_H - 1) * IMG_W;
    }

    f2 acc[NH];
#pragma unroll
    for (int j = 0; j < NH; ++j) acc[j] = (f2){0.0f, 0.0f};

#pragma unroll
    for (int c = 0; c < NC; ++c) {
        const float* __restrict__ pc = imgs + ((size_t)b * NC + c) * IMG_HW;
        const f2 x = ld2(pc + r0 + w0);

        f2 nbv[NH];

        // di = 0: d = 1 (t=0, odd) or 8 (t=1, even). For odd d, load aligned
        // pairs at w0-d-1 / w0 / w0+d+1 and shift-combine; all loads stay 8B-aligned.
        {
            const int d  = dils[0];
            const int a  = w0 - d - od;
            const int bq = w0 + d + od;
            const float* __restrict__ pm = pc + rm[0];
            const float* __restrict__ p0 = pc + r0;
            const float* __restrict__ pp = pc + rp[0];
            const f2 Pm = ldP(pm, a), Cm = ld2(pm + w0), Qm = ldQ(pm, bq);
            const f2 P0 = ldP(p0, a),                    Q0 = ldQ(p0, bq);
            const f2 Pp = ldP(pp, a), Cp = ld2(pp + w0), Qp = ldQ(pp, bq);
            nbv[0] = t ? Pm : (f2){Pm.y, Cm.x};
            nbv[1] = Cm;
            nbv[2] = t ? Qm : (f2){Cm.y, Qm.x};
            nbv[3] = t ? P0 : (f2){P0.y, x.x};
            nbv[4] = t ? Q0 : (f2){x.y, Q0.x};
            nbv[5] = t ? Pp : (f2){Pp.y, Cp.x};
            nbv[6] = Cp;
            nbv[7] = t ? Qp : (f2){Cp.y, Qp.x};
        }

        // di = 1,2: even d for both halves -> direct aligned pairs
#pragma unroll
        for (int di = 1; di < 3; ++di) {
            const int d = dils[di];
            const float* __restrict__ pm = pc + rm[di];
            const float* __restrict__ p0 = pc + r0;
            const float* __restrict__ pp = pc + rp[di];
            nbv[di*8+0] = ldP(pm, w0 - d);
            nbv[di*8+1] = ld2(pm + w0);
            nbv[di*8+2] = ldQ(pm, w0 + d);
            nbv[di*8+3] = ldP(p0, w0 - d);
            nbv[di*8+4] = ldQ(p0, w0 + d);
            nbv[di*8+5] = ldP(pp, w0 - d);
            nbv[di*8+6] = ld2(pp + w0);
            nbv[di*8+7] = ldQ(pp, w0 + d);
        }

        // partial stats over my 24 taps (per pixel component); combine halves -> 48
        f2 s0 = (f2){0,0}, s1 = (f2){0,0}, q0 = (f2){0,0}, q1 = (f2){0,0};
#pragma unroll
        for (int j = 0; j < NH; j += 2) {
            s0 += nbv[j];
            s1 += nbv[j+1];
            q0 += nbv[j]   * nbv[j];
            q1 += nbv[j+1] * nbv[j+1];
        }
        f2 s  = s0 + s1;
        f2 ss = q0 + q1;
        s.x  += __shfl_xor(s.x,  32);
        s.y  += __shfl_xor(s.y,  32);
        ss.x += __shfl_xor(ss.x, 32);
        ss.y += __shfl_xor(ss.y, 32);

        f2 scl;
#pragma unroll
        for (int i = 0; i < 2; ++i) {
            const float mean = s[i] * (1.0f / 48.0f);
            const float var  = fmaxf((ss[i] - s[i] * mean) * (1.0f / 47.0f), 0.0f);
            scl[i] = __builtin_amdgcn_rcpf(
                         fmaf(__builtin_amdgcn_sqrtf(var), 0.3f, 3.0e-9f));
        }
        const f2 xs = x * scl;

#pragma unroll
        for (int j = 0; j < NH; ++j) {
            const f2 dd = nbv[j] * scl - xs;
            acc[j] += dd * dd;
        }
    }

    // softmax over all 48: max(aff) == min(acc); cross-half via shfl
    f2 m0, m1, m2, m3;
#pragma unroll
    for (int i = 0; i < 2; ++i) {
        m0[i] = fminf(acc[0][i], acc[1][i]);
        m1[i] = fminf(acc[2][i], acc[3][i]);
        m2[i] = fminf(acc[4][i], acc[5][i]);
        m3[i] = fminf(acc[6][i], acc[7][i]);
    }
#pragma unroll
    for (int j = 8; j < NH; j += 8) {
#pragma unroll
        for (int i = 0; i < 2; ++i) {
            m0[i] = fminf(m0[i], fminf(acc[j+0][i], acc[j+1][i]));
            m1[i] = fminf(m1[i], fminf(acc[j+2][i], acc[j+3][i]));
            m2[i] = fminf(m2[i], fminf(acc[j+4][i], acc[j+5][i]));
            m3[i] = fminf(m3[i], fminf(acc[j+6][i], acc[j+7][i]));
        }
    }
    f2 mn;
#pragma unroll
    for (int i = 0; i < 2; ++i) {
        mn[i] = fminf(fminf(m0[i], m1[i]), fminf(m2[i], m3[i]));
        mn[i] = fminf(mn[i], __shfl_xor(mn[i], 32));
    }

    const float SC = (1.0f / 3.0f) * 1.44269504f;   // /3 then ln->log2
    const f2 mnSC = mn * SC;
    f2 e0 = (f2){0,0}, e1 = (f2){0,0}, e2 = (f2){0,0}, e3 = (f2){0,0};
#pragma unroll
    for (int j = 0; j < NH; j += 4) {
#pragma unroll
        for (int i = 0; i < 2; ++i) {
            acc[j+0][i] = __builtin_amdgcn_exp2f(fmaf(acc[j+0][i], -SC, mnSC[i]));
            acc[j+1][i] = __builtin_amdgcn_exp2f(fmaf(acc[j+1][i], -SC, mnSC[i]));
            acc[j+2][i] = __builtin_amdgcn_exp2f(fmaf(acc[j+2][i], -SC, mnSC[i]));
            acc[j+3][i] = __builtin_amdgcn_exp2f(fmaf(acc[j+3][i], -SC, mnSC[i]));
        }
        e0 += acc[j+0]; e1 += acc[j+1]; e2 += acc[j+2]; e3 += acc[j+3];
    }
    f2 se = (e0 + e1) + (e2 + e3);
    f2 inv;
#pragma unroll
    for (int i = 0; i < 2; ++i) {
        se[i] += __shfl_xor(se[i], 32);
        inv[i] = __builtin_amdgcn_rcpf(se[i]);
    }

    float* __restrict__ op = out + ((size_t)(b * NK + t * NH)) * IMG_HW + r0 + w0;
#pragma unroll
    for (int j = 0; j < NH; ++j) {
        const float pav = t ? pa.v[NH + j] : pa.v[j];
        const f2 v = acc[j] * inv + pav;
        __builtin_nontemporal_store(v, (f2*)(op + (size_t)j * IMG_HW));
    }
}

static void compute_pos_add(float* out48)
{
    const int DIL[6] = {1, 2, 4, 8, 12, 24};
    const double SQ2 = 1.4142135623730951;
    const double diag[8] = {SQ2, 1.0, SQ2, 1.0, 1.0, SQ2, 1.0, SQ2};

    double pos[NK];
    for (int di = 0; di < 6; ++di)
        for (int tp = 0; tp < 8; ++tp)
            pos[di * 8 + tp] = (double)((float)(diag[tp] * DIL[di]));  // match fp32 concat

    double s = 0.0;
    for (int k = 0; k < NK; ++k) s += pos[k];
    const double m = s / NK;
    double v = 0.0;
    for (int k = 0; k < NK; ++k) { const double d = pos[k] - m; v += d * d; }
    v /= (NK - 1);
    const double stdv = sqrt(v);

    double aff[NK];
    double mx = -1e300;
    for (int k = 0; k < NK; ++k) {
        const double q = pos[k] / ((stdv + 1e-8) * 0.3);
        aff[k] = -(q * q);
        if (aff[k] > mx) mx = aff[k];
    }
    double se = 0.0;
    for (int k = 0; k < NK; ++k) { aff[k] = exp(aff[k] - mx); se += aff[k]; }
    for (int k = 0; k < NK; ++k) out48[k] = (float)(0.01 * aff[k] / se);
}

extern "C" void kernel_launch(void* const* d_in, const int* in_sizes, int n_in,
                              void* d_out, int out_size, void* d_ws, size_t ws_size,
                              hipStream_t stream)
{
    const float* imgs = (const float*)d_in[0];
    float* out = (float*)d_out;

    PosAdd pa;
    compute_pos_add(pa.v);

    // 2 thread-slots per pixel (k-split across lane halves), 2 pixels per thread
    const int blocks = (NB * IMG_H * IMG_W * 2) / (256 * 2);   // 2304
    LLA_41412074668179_kernel<<<blocks, 256, 0, stream>>>(imgs, out, pa);
}

// Round 4
// 36.946 us; speedup vs baseline: 1.5406x; 1.5406x over previous
//
#include <hip/hip_runtime.h>
#include <math.h>

#define IMG_H  384
#define IMG_W  384
#define IMG_HW (IMG_H * IMG_W)
#define NB     4
#define NC     3
#define NK     48
#define NH     24          /* taps per lane-half */

typedef float f2 __attribute__((ext_vector_type(2)));

struct PosAdd { float v[NK]; };

/* 8B-aligned pair load: caller guarantees even offset from an 8B-aligned base */
__device__ __forceinline__ f2 ld2(const float* __restrict__ p) {
    return *(const f2* __restrict__)p;
}

/* BRANCHLESS left pair: columns (a, a+1) clamped at 0; a is even (may be <0).
   Clamped cases collapse to (rowp[0], rowp[0]) = (L.x, L.x). */
__device__ __forceinline__ f2 ldP(const float* __restrict__ rowp, int a) {
    const f2 L = ld2(rowp + (a > 0 ? a : 0));          /* v_max_i32 */
    f2 r;
    r.x = L.x;
    r.y = (a < 0) ? L.x : L.y;                         /* v_cndmask */
    return r;
}

/* BRANCHLESS right pair: columns (bq, bq+1) clamped at W-1; bq is even.
   Clamped cases collapse to (rowp[W-1], rowp[W-1]) = (L.y, L.y). */
__device__ __forceinline__ f2 ldQ(const float* __restrict__ rowp, int bq) {
    const f2 L = ld2(rowp + (bq < IMG_W - 2 ? bq : IMG_W - 2));  /* v_min_i32 */
    f2 r;
    r.x = (bq > IMG_W - 2) ? L.y : L.x;                /* v_cndmask */
    r.y = L.y;
    return r;
}

__global__ __launch_bounds__(256) void LLA_41412074668179_kernel(
    const float* __restrict__ imgs, float* __restrict__ out, PosAdd pa)
{
    const int tid  = threadIdx.x;
    const int lane = tid & 63;
    const int t    = lane >> 5;              // 0 -> dil{1,2,4}=k0..23, 1 -> dil{8,12,24}=k24..47

    // XCD-chunked swizzle: 2304 blocks = 8 XCDs x 288 (contiguous row chunks per XCD)
    const int lb = (blockIdx.x & 7) * 288 + (blockIdx.x >> 3);

    // 2 consecutive pixels per thread, w0 even; half-wave covers 64 consecutive px,
    // both halves same pixels. 64-px segments never straddle a row (384 % 64 == 0).
    const int px0 = lb * 256 + (tid >> 6) * 64 + (lane & 31) * 2;
    const int w0 = px0 % IMG_W;
    const int hb = px0 / IMG_W;
    const int h  = hb % IMG_H;
    const int b  = hb / IMG_H;

    const int dils[3] = { t ? 8 : 1, t ? 12 : 2, t ? 24 : 4 };
    const int od = t ? 0 : 1;                // di==0 dilation is odd only for t==0 (d=1)

    const int r0 = h * IMG_W;
    int rm[3], rp[3];
#pragma unroll
    for (int di = 0; di < 3; ++di) {
        const int d = dils[di];
        rm[di] = max(h - d, 0) * IMG_W;
        rp[di] = min(h + d, IMG_H - 1) * IMG_W;
    }

    f2 acc[NH];
#pragma unroll
    for (int j = 0; j < NH; ++j) acc[j] = (f2){0.0f, 0.0f};

#pragma unroll
    for (int c = 0; c < NC; ++c) {
        const float* __restrict__ pc = imgs + ((size_t)b * NC + c) * IMG_HW;
        const f2 x = ld2(pc + r0 + w0);

        f2 nbv[NH];

        // di = 0: d = 1 (t=0, odd) or 8 (t=1, even). For odd d, load aligned
        // pairs at w0-2 / w0 / w0+2 and shift-combine; all loads stay 8B-aligned.
        {
            const int a  = w0 - dils[0] - od;     // even
            const int bq = w0 + dils[0] + od;     // even
            const float* __restrict__ pm = pc + rm[0];
            const float* __restrict__ p0 = pc + r0;
            const float* __restrict__ pp = pc + rp[0];
            const f2 Pm = ldP(pm, a), Cm = ld2(pm + w0), Qm = ldQ(pm, bq);
            const f2 P0 = ldP(p0, a),                    Q0 = ldQ(p0, bq);
            const f2 Pp = ldP(pp, a), Cp = ld2(pp + w0), Qp = ldQ(pp, bq);
            nbv[0] = t ? Pm : (f2){Pm.y, Cm.x};
            nbv[1] = Cm;
            nbv[2] = t ? Qm : (f2){Cm.y, Qm.x};
            nbv[3] = t ? P0 : (f2){P0.y, x.x};
            nbv[4] = t ? Q0 : (f2){x.y, Q0.x};
            nbv[5] = t ? Pp : (f2){Pp.y, Cp.x};
            nbv[6] = Cp;
            nbv[7] = t ? Qp : (f2){Cp.y, Qp.x};
        }

        // di = 1,2: even d for both halves -> direct aligned pairs
#pragma unroll
        for (int di = 1; di < 3; ++di) {
            const int d = dils[di];
            const float* __restrict__ pm = pc + rm[di];
            const float* __restrict__ p0 = pc + r0;
            const float* __restrict__ pp = pc + rp[di];
            nbv[di*8+0] = ldP(pm, w0 - d);
            nbv[di*8+1] = ld2(pm + w0);
            nbv[di*8+2] = ldQ(pm, w0 + d);
            nbv[di*8+3] = ldP(p0, w0 - d);
            nbv[di*8+4] = ldQ(p0, w0 + d);
            nbv[di*8+5] = ldP(pp, w0 - d);
            nbv[di*8+6] = ld2(pp + w0);
            nbv[di*8+7] = ldQ(pp, w0 + d);
        }

        // partial stats over my 24 taps (per pixel component); combine halves -> 48
        f2 s0 = (f2){0,0}, s1 = (f2){0,0}, q0 = (f2){0,0}, q1 = (f2){0,0};
#pragma unroll
        for (int j = 0; j < NH; j += 2) {
            s0 += nbv[j];
            s1 += nbv[j+1];
            q0 += nbv[j]   * nbv[j];
            q1 += nbv[j+1] * nbv[j+1];
        }
        f2 s  = s0 + s1;
        f2 ss = q0 + q1;
        s.x  += __shfl_xor(s.x,  32);
        s.y  += __shfl_xor(s.y,  32);
        ss.x += __shfl_xor(ss.x, 32);
        ss.y += __shfl_xor(ss.y, 32);

        f2 scl;
#pragma unroll
        for (int i = 0; i < 2; ++i) {
            const float mean = s[i] * (1.0f / 48.0f);
            const float var  = fmaxf((ss[i] - s[i] * mean) * (1.0f / 47.0f), 0.0f);
            scl[i] = __builtin_amdgcn_rcpf(
                         fmaf(__builtin_amdgcn_sqrtf(var), 0.3f, 3.0e-9f));
        }
        const f2 xs = x * scl;

#pragma unroll
        for (int j = 0; j < NH; ++j) {
            const f2 dd = nbv[j] * scl - xs;
            acc[j] += dd * dd;
        }
    }

    // softmax over all 48: max(aff) == min(acc); cross-half via shfl
    f2 m0, m1, m2, m3;
#pragma unroll
    for (int i = 0; i < 2; ++i) {
        m0[i] = fminf(acc[0][i], acc[1][i]);
        m1[i] = fminf(acc[2][i], acc[3][i]);
        m2[i] = fminf(acc[4][i], acc[5][i]);
        m3[i] = fminf(acc[6][i], acc[7][i]);
    }
#pragma unroll
    for (int j = 8; j < NH; j += 8) {
#pragma unroll
        for (int i = 0; i < 2; ++i) {
            m0[i] = fminf(m0[i], fminf(acc[j+0][i], acc[j+1][i]));
            m1[i] = fminf(m1[i], fminf(acc[j+2][i], acc[j+3][i]));
            m2[i] = fminf(m2[i], fminf(acc[j+4][i], acc[j+5][i]));
            m3[i] = fminf(m3[i], fminf(acc[j+6][i], acc[j+7][i]));
        }
    }
    f2 mn;
#pragma unroll
    for (int i = 0; i < 2; ++i) {
        mn[i] = fminf(fminf(m0[i], m1[i]), fminf(m2[i], m3[i]));
        mn[i] = fminf(mn[i], __shfl_xor(mn[i], 32));
    }

    const float SC = (1.0f / 3.0f) * 1.44269504f;   // /3 then ln->log2
    const f2 mnSC = mn * SC;
    f2 e0 = (f2){0,0}, e1 = (f2){0,0}, e2 = (f2){0,0}, e3 = (f2){0,0};
#pragma unroll
    for (int j = 0; j < NH; j += 4) {
#pragma unroll
        for (int i = 0; i < 2; ++i) {
            acc[j+0][i] = __builtin_amdgcn_exp2f(fmaf(acc[j+0][i], -SC, mnSC[i]));
            acc[j+1][i] = __builtin_amdgcn_exp2f(fmaf(acc[j+1][i], -SC, mnSC[i]));
            acc[j+2][i] = __builtin_amdgcn_exp2f(fmaf(acc[j+2][i], -SC, mnSC[i]));
            acc[j+3][i] = __builtin_amdgcn_exp2f(fmaf(acc[j+3][i], -SC, mnSC[i]));
        }
        e0 += acc[j+0]; e1 += acc[j+1]; e2 += acc[j+2]; e3 += acc[j+3];
    }
    f2 se = (e0 + e1) + (e2 + e3);
    f2 inv;
#pragma unroll
    for (int i = 0; i < 2; ++i) {
        se[i] += __shfl_xor(se[i], 32);
        inv[i] = __builtin_amdgcn_rcpf(se[i]);
    }

    float* __restrict__ op = out + ((size_t)(b * NK + t * NH)) * IMG_HW + r0 + w0;
#pragma unroll
    for (int j = 0; j < NH; ++j) {
        const float pav = t ? pa.v[NH + j] : pa.v[j];
        const f2 v = acc[j] * inv + pav;
        __builtin_nontemporal_store(v, (f2*)(op + (size_t)j * IMG_HW));
    }
}

static void compute_pos_add(float* out48)
{
    const int DIL[6] = {1, 2, 4, 8, 12, 24};
    const double SQ2 = 1.4142135623730951;
    const double diag[8] = {SQ2, 1.0, SQ2, 1.0, 1.0, SQ2, 1.0, SQ2};

    double pos[NK];
    for (int di = 0; di < 6; ++di)
        for (int tp = 0; tp < 8; ++tp)
            pos[di * 8 + tp] = (double)((float)(diag[tp] * DIL[di]));  // match fp32 concat

    double s = 0.0;
    for (int k = 0; k < NK; ++k) s += pos[k];
    const double m = s / NK;
    double v = 0.0;
    for (int k = 0; k < NK; ++k) { const double d = pos[k] - m; v += d * d; }
    v /= (NK - 1);
    const double stdv = sqrt(v);

    double aff[NK];
    double mx = -1e300;
    for (int k = 0; k < NK; ++k) {
        const double q = pos[k] / ((stdv + 1e-8) * 0.3);
        aff[k] = -(q * q);
        if (aff[k] > mx) mx = aff[k];
    }
    double se = 0.0;
    for (int k = 0; k < NK; ++k) { aff[k] = exp(aff[k] - mx); se += aff[k]; }
    for (int k = 0; k < NK; ++k) out48[k] = (float)(0.01 * aff[k] / se);
}

extern "C" void kernel_launch(void* const* d_in, const int* in_sizes, int n_in,
                              void* d_out, int out_size, void* d_ws, size_t ws_size,
                              hipStream_t stream)
{
    const float* imgs = (const float*)d_in[0];
    float* out = (float*)d_out;

    PosAdd pa;
    compute_pos_add(pa.v);

    // 2 thread-slots per pixel (k-split across lane halves), 2 pixels per thread
    const int blocks = (NB * IMG_H * IMG_W * 2) / (256 * 2);   // 2304
    LLA_41412074668179_kernel<<<blocks, 256, 0, stream>>>(imgs, out, pa);
}